// Round 1
// baseline (99.062 us; speedup 1.0000x reference)
//
#include <hip/hip_runtime.h>

// TcEmbedding: x (B=4, S=4096, D=64) f32.
// norms[b,t] = sum_d |x[b,t,d]|
// tc[b,t]   = t - j, j = nearest index < t with norms[j] < 0.7*(norms[t]+1e-8), else 0.
//
// R10: single-dispatch per-batch fusion, NO device sync, NO workspace.
// Grid = B*4 blocks of 1024 threads. Block (b,q) self-computes all norms it
// can ever need (rows [0,(q+1)*1024) of batch b -> f64 LDS, 32KB), then the
// chunk minima, then scans its quarter of t's with the same two-level ballot
// search as R7's kernel B, entirely from LDS.
// Rationale: R7's ~14us controllable cost is two graph-node launches + gap;
// each kernel only reads 4MB total. Fusing removes one node+gap. Unlike R6
// (256 blocks x ~0.5MB replicated = 128MB aggregate, contention wall at
// ~3TB/s), this replicates only 4x per batch: 16 blocks, <=1MB each, 16MB
// aggregate, L3-resident. Critical block streams 1MB coalesced with 8-deep
// float4 pipelining (~128KB in flight/CU) -> ~4-5us expected.
// Ledger (all measured worse): R4 coop grid.sync +45us; R5 acquire spin
// +40us; R8 atomic-counter barrier +14us; R6 256-block full recompute
// kernel 43us; R9 self-contained B +1.9us.
// f64 norms/compares throughout: a compare flip near the 0.7 threshold
// changes tc by O(S) >> absmax tolerance (absmax 0 every round R1-R10).

#define SS 4096
typedef unsigned long long u64;

__global__ void __launch_bounds__(1024)
tc_fused_kernel(const float4* __restrict__ x4, float* __restrict__ out)
{
    __shared__ double sn[SS];    // norms of this batch, rows [0,(q+1)*1024)
    __shared__ double scm[64];   // chunk minima, chunks [0,(q+1)*16)

    const int bi   = blockIdx.x;
    const int b    = bi >> 2;           // batch
    const int q    = bi & 3;            // quarter of t-range this block owns
    const int wave = threadIdx.x >> 6;
    const int lane = threadIdx.x & 63;
    const int g    = lane >> 4;         // row within wave's 4 (0..3)
    const int e    = lane & 15;         // float4 index within row

    const int R = (q + 1) * 16;         // rounds of 64 rows (= chunks valid)
    const float4* xb = x4 + (size_t)b * SS * 16;

    // ---- Phase 1: norms. Round r: 16 waves cover rows r*64..r*64+63,
    // contiguous 16KB, coalesced. Unroll 8 -> 8 float4 loads in flight per
    // lane (128KB/CU) to hide HBM/L3 latency.
    #pragma unroll 8
    for (int r = 0; r < R; ++r) {
        int row = (r << 6) + (wave << 2) + g;
        float4 p = xb[row * 16 + e];
        double a = (double)fabsf(p.x) + (double)fabsf(p.y)
                 + (double)fabsf(p.z) + (double)fabsf(p.w);
        #pragma unroll
        for (int off = 8; off > 0; off >>= 1)   // reduce within 16-lane group
            a += __shfl_xor(a, off, 64);
        if (e == 0) sn[row] = a;                // one writer per row
    }
    __syncthreads();

    // ---- Phase 2: chunk minima (order-independent min, compare-identical
    // to R7's kernel A). One wave per chunk, strided.
    for (int c = wave; c < R; c += 16) {
        double m = sn[(c << 6) + lane];
        #pragma unroll
        for (int off = 32; off > 0; off >>= 1) {
            double o = __shfl_xor(m, off, 64);
            m = (o < m) ? o : m;
        }
        if (lane == 0) scm[c] = m;
    }
    __syncthreads();

    // ---- Phase 3: two-level ballot search, one wave per chunk.
    {
        const int c = (q << 4) + wave;          // chunk in batch (0..63)
        const double v  = sn[(c << 6) + lane];  // own chunk's 64 norms
        const double cm = (lane < c) ? scm[lane] : 1e300; // pre-masked minima
        float myres = 0.f;
        for (int pos = 0; pos < 64; ++pos) {    // t = c*64 + pos
            double thr = 0.7 * (__shfl(v, pos, 64) + 1e-8);
            int r = 0;
            // (a) partial current chunk: j in [c*64, t)
            u64 m = __ballot(lane < pos && v < thr);
            if (m) {                            // wave-uniform branch
                r = pos - (63 - __clzll(m));
            } else {
                // (b) nearest earlier chunk whose min qualifies
                u64 mc = __ballot(cm < thr);
                if (mc) {
                    int cc = 63 - __clzll(mc);  // wave-uniform
                    // (c) nearest element in that chunk (non-empty by cmin)
                    double v2 = sn[(cc << 6) + lane];
                    u64 m2 = __ballot(v2 < thr);
                    r = ((c - cc) << 6) + pos - (63 - __clzll(m2));
                }
            }
            if (lane == pos) myres = (float)r;
        }
        out[(b << 12) + (c << 6) + lane] = myres;
    }
}

extern "C" void kernel_launch(void* const* d_in, const int* in_sizes, int n_in,
                              void* d_out, int out_size, void* d_ws, size_t ws_size,
                              hipStream_t stream) {
    (void)d_ws; (void)ws_size; (void)n_in; (void)out_size;
    const float4* x4 = (const float4*)d_in[0];
    float* out = (float*)d_out;
    int nrows = in_sizes[0] / 64;       // B*S = 16384
    int nb    = nrows / SS;             // batches = 4
    tc_fused_kernel<<<nb * 4, 1024, 0, stream>>>(x4, out);
}

// Round 3
// 83.349 us; speedup vs baseline: 1.1885x; 1.1885x over previous
//
#include <hip/hip_runtime.h>

// TcEmbedding: x (B=4, S=4096, D=64) f32.
// norms[b,t] = sum_d |x[b,t,d]|
// tc[b,t]   = t - j, j = nearest index < t with norms[j] < 0.7*(norms[t]+1e-8), else 0.
//
// R11 (resubmit — previous round was an infra failure, kernel never ran):
// single-dispatch, sync-free, 256 blocks (one per 64-t chunk, like R7's
// kernel B grid). Each block recomputes every norm in its prefix from x into
// LDS (<=32KB f64), takes chunk minima, then runs R7's two-level ballot
// search entirely from LDS. No workspace, no cross-block traffic.
//
// Why this beats R10 (fused 16-block, 57us kernel): R10's VGPR_Count=20
// proved the unroll-8 never became in-flight loads -> each wave was a
// ~64-step serial latency chain (load -> f64 shuffle-reduce -> repeat), and
// phase 3 gave each wave 64 serial ballot positions. R10's FETCH=5.1MB at
// 1.1% HBM also proved the redundant-read aggregate is cache-absorbed, so
// the sync-free structure is sound -- only the parallelism shape was wrong.
// R11 restores R7's shape: worst block does 4 rounds; in each round a wave
// computes a WHOLE chunk with lane-per-row contiguous reads (16 float4/lane,
// two 8-register batches explicitly live -> real memory-level parallelism,
// zero cross-lane ops in the load loop), then ONE 6-stage wave reduce per
// chunk for the min (12 DS ops/chunk vs R10's 8 DS ops/row).
// Ledger (measured): R4 coop sync +45us; R5 spin +40us; R8 atomic ctr +14us;
// R6 256-blk recompute (bad shape) 43us; R9 self-contained B +1.9us;
// R10 16-blk fusion kernel 57us. R7 two-dispatch baseline = 57.2us total.
// f64 norms/compares throughout: a compare flip near the 0.7 threshold
// changes tc by O(S) >> absmax tolerance (absmax 0 every round R1-R10).

#define SS 4096
typedef unsigned long long u64;

__global__ void __launch_bounds__(1024)
tc_onepass_kernel(const float4* __restrict__ x4, float* __restrict__ out)
{
    __shared__ double sn[SS];    // prefix norms, rows [0,(c+1)*64)
    __shared__ double scm[64];   // chunk minima, chunks [0,c]

    const int ci   = blockIdx.x;        // chunk id = b*64 + c
    const int b    = ci >> 6;
    const int c    = ci & 63;
    const int wave = threadIdx.x >> 6;
    const int lane = threadIdx.x & 63;
    const float4* xb = x4 + (size_t)b * (SS * 16);

    // ---- Phase 1: norms + chunk minima for chunks 0..c.
    // Round r: wave w computes chunk k=r*16+w; lane l owns row k*64+l and
    // reads its 256B contiguously (16 float4). No cross-lane ops until the
    // single per-chunk min reduce.
    #pragma unroll
    for (int r = 0; r < 4; ++r) {
        const int k = (r << 4) + wave;
        if (k <= c) {                   // wave-uniform guard, barrier outside
            const float4* rp = xb + (size_t)((k << 6) + lane) * 16;
            float4 pa[8], pb[8];
            #pragma unroll
            for (int i = 0; i < 8; ++i) pa[i] = rp[i];
            #pragma unroll
            for (int i = 0; i < 8; ++i) pb[i] = rp[8 + i];
            double a0 = 0.0, a1 = 0.0, a2 = 0.0, a3 = 0.0;
            #pragma unroll
            for (int i = 0; i < 8; i += 4) {
                a0 += (double)fabsf(pa[i    ].x) + (double)fabsf(pa[i    ].y)
                    + (double)fabsf(pa[i    ].z) + (double)fabsf(pa[i    ].w);
                a1 += (double)fabsf(pa[i + 1].x) + (double)fabsf(pa[i + 1].y)
                    + (double)fabsf(pa[i + 1].z) + (double)fabsf(pa[i + 1].w);
                a2 += (double)fabsf(pa[i + 2].x) + (double)fabsf(pa[i + 2].y)
                    + (double)fabsf(pa[i + 2].z) + (double)fabsf(pa[i + 2].w);
                a3 += (double)fabsf(pa[i + 3].x) + (double)fabsf(pa[i + 3].y)
                    + (double)fabsf(pa[i + 3].z) + (double)fabsf(pa[i + 3].w);
            }
            #pragma unroll
            for (int i = 0; i < 8; i += 4) {
                a0 += (double)fabsf(pb[i    ].x) + (double)fabsf(pb[i    ].y)
                    + (double)fabsf(pb[i    ].z) + (double)fabsf(pb[i    ].w);
                a1 += (double)fabsf(pb[i + 1].x) + (double)fabsf(pb[i + 1].y)
                    + (double)fabsf(pb[i + 1].z) + (double)fabsf(pb[i + 1].w);
                a2 += (double)fabsf(pb[i + 2].x) + (double)fabsf(pb[i + 2].y)
                    + (double)fabsf(pb[i + 2].z) + (double)fabsf(pb[i + 2].w);
                a3 += (double)fabsf(pb[i + 3].x) + (double)fabsf(pb[i + 3].y)
                    + (double)fabsf(pb[i + 3].z) + (double)fabsf(pb[i + 3].w);
            }
            const double a = (a0 + a1) + (a2 + a3);
            sn[(k << 6) + lane] = a;
            double m = a;               // one full-wave min reduce per chunk
            #pragma unroll
            for (int off = 32; off > 0; off >>= 1) {
                double o = __shfl_xor(m, off, 64);
                m = (o < m) ? o : m;
            }
            if (lane == 0) scm[k] = m;
        }
    }
    __syncthreads();

    // ---- Phase 2: R7 kernel-B two-level ballot search, LDS-sourced.
    {
        const double v  = sn[(c << 6) + lane];
        const double cm = (lane < c) ? scm[lane] : 1e300;
        float res[4];
        #pragma unroll
        for (int k2 = 0; k2 < 4; ++k2) {
            const int pos = (wave << 2) + k2;   // t = c*64 + pos
            const double thr = 0.7 * (sn[(c << 6) + pos] + 1e-8);
            int r = 0;
            // (a) partial current chunk: j in [c*64, t)
            u64 m = __ballot(lane < pos && v < thr);
            if (m) {                            // wave-uniform branch
                r = pos - (63 - __clzll(m));
            } else {
                // (b) nearest earlier chunk whose min qualifies
                u64 mc = __ballot(lane < c && cm < thr);
                if (mc) {
                    int cc = 63 - __clzll(mc);  // wave-uniform
                    // (c) nearest element in that chunk (non-empty by cmin)
                    double v2 = sn[(cc << 6) + lane];
                    u64 m2 = __ballot(v2 < thr);
                    r = ((c - cc) << 6) + pos - (63 - __clzll(m2));
                }
            }
            res[k2] = (float)r;
        }
        if (lane == 0)
            ((float4*)out)[ci * 16 + wave] =
                make_float4(res[0], res[1], res[2], res[3]);
    }
}

extern "C" void kernel_launch(void* const* d_in, const int* in_sizes, int n_in,
                              void* d_out, int out_size, void* d_ws, size_t ws_size,
                              hipStream_t stream) {
    (void)d_ws; (void)ws_size; (void)n_in; (void)out_size;
    const float4* x4 = (const float4*)d_in[0];
    float* out = (float*)d_out;
    int nrows  = in_sizes[0] / 64;      // B*S = 16384
    int nchunk = nrows / 64;            // 256
    tc_onepass_kernel<<<nchunk, 1024, 0, stream>>>(x4, out);
}

// Round 4
// 82.179 us; speedup vs baseline: 1.2054x; 1.0142x over previous
//
#include <hip/hip_runtime.h>

// TcEmbedding: x (B=4, S=4096, D=64) f32.
// norms[b,t] = sum_d |x[b,t,d]|
// tc[b,t]   = t - j, j = nearest index < t with norms[j] < 0.7*(norms[t]+1e-8), else 0.
//
// R12: single-dispatch, sync-free, 256 blocks (one per 64-t chunk). Each
// block recomputes its prefix norms into LDS, then chunk minima, then R7's
// two-level ballot search from LDS. Differs from R11 ONLY in the phase-1
// access pattern:
//   R11 (40us): lane-per-row, 16 float4/lane at stride 256B across lanes ->
//     each load instr touches 64 cache lines (16B used each); 16 waves x
//     256KB round footprint thrash the 32KB L1 -> MSHR-limited ~25 GB/s/CU.
//   R12: round k reads chunk k CONTIGUOUSLY: thread tid loads
//     xb[(k<<10)+tid] (16KB coalesced, 16 fully-consumed lines/instr), then
//     the PROVEN R7-A reduce (|x|+|y|+|z|+|w| in f64, xor-8/4/2/1 16-lane) —
//     identical summation order => identical compare outcomes (absmax 0).
//   Worst block streams 1MB coalesced at per-CU L2 rate ~140 GB/s => ~7us.
// R10 data: single-node graph overhead ~1us (99.1 total - 41 fill - 57
// kernel), so a ~9us one-pass beats R7's two-node 14us launch+gap.
// Ledger (measured): R4 coop sync +45us; R5 spin +40us; R8 atomic ctr
// +14us; R6 256-blk scatter recompute 43us; R9 self-contained B +1.9us;
// R10 16-blk fusion (VGPR=20 serial chain) kernel 57us; R11 256-blk
// scatter recompute kernel ~40us. R7 two-dispatch baseline = 57.2us total.
// f64 norms/compares throughout: a compare flip near the 0.7 threshold
// changes tc by O(S) >> absmax tolerance (absmax 0 every round R1-R11).

#define SS 4096
typedef unsigned long long u64;

__global__ void __launch_bounds__(1024)
tc_onepass_kernel(const float4* __restrict__ x4, float* __restrict__ out)
{
    __shared__ double sn[SS];    // prefix norms, rows [0, kmax*64)
    __shared__ double scm[64];   // chunk minima

    const int ci   = blockIdx.x;        // chunk id = b*64 + c
    const int b    = ci >> 6;
    const int c    = ci & 63;
    const int tid  = threadIdx.x;
    const int wave = tid >> 6;
    const int lane = tid & 63;
    const int e    = tid & 15;          // 16-lane group element
    const int row_in_chunk = tid >> 4;  // 0..63
    const float4* xb = x4 + (size_t)b * (SS * 16);

    // Rounds of whole chunks, rounded up to x4 for the unroll. Chunks
    // (c, kmax) are valid memory (same batch); their sn/scm entries are
    // computed but masked off in phase 2.
    const int kmax = (c + 4) & ~3;      // c=63 -> 64; c=0 -> 4

    // ---- Phase 1: norms. Round k: 1024 threads read chunk k contiguously
    // (16KB, float4 per thread), 16-lane xor reduce -> 64 row norms.
    for (int k = 0; k < kmax; k += 4) {
        const float4 p0 = xb[((k + 0) << 10) + tid];
        const float4 p1 = xb[((k + 1) << 10) + tid];
        const float4 p2 = xb[((k + 2) << 10) + tid];
        const float4 p3 = xb[((k + 3) << 10) + tid];
        double a0 = (double)fabsf(p0.x) + (double)fabsf(p0.y)
                  + (double)fabsf(p0.z) + (double)fabsf(p0.w);
        double a1 = (double)fabsf(p1.x) + (double)fabsf(p1.y)
                  + (double)fabsf(p1.z) + (double)fabsf(p1.w);
        double a2 = (double)fabsf(p2.x) + (double)fabsf(p2.y)
                  + (double)fabsf(p2.z) + (double)fabsf(p2.w);
        double a3 = (double)fabsf(p3.x) + (double)fabsf(p3.y)
                  + (double)fabsf(p3.z) + (double)fabsf(p3.w);
        #pragma unroll
        for (int off = 8; off > 0; off >>= 1) {  // R7-A reduce order
            a0 += __shfl_xor(a0, off, 64);
            a1 += __shfl_xor(a1, off, 64);
            a2 += __shfl_xor(a2, off, 64);
            a3 += __shfl_xor(a3, off, 64);
        }
        if (e == 0) {
            sn[((k + 0) << 6) + row_in_chunk] = a0;
            sn[((k + 1) << 6) + row_in_chunk] = a1;
            sn[((k + 2) << 6) + row_in_chunk] = a2;
            sn[((k + 3) << 6) + row_in_chunk] = a3;
        }
    }
    __syncthreads();

    // ---- Phase 1.5: chunk minima (order-independent min). Wave w handles
    // chunks w, w+16, w+32, w+48 (those < kmax).
    for (int k = wave; k < kmax; k += 16) {
        double m = sn[(k << 6) + lane];
        #pragma unroll
        for (int off = 32; off > 0; off >>= 1) {
            double o = __shfl_xor(m, off, 64);
            m = (o < m) ? o : m;
        }
        if (lane == 0) scm[k] = m;
    }
    __syncthreads();

    // ---- Phase 2: R7 kernel-B two-level ballot search, LDS-sourced.
    {
        const double v  = sn[(c << 6) + lane];
        const double cm = (lane < c) ? scm[lane] : 1e300;
        float res[4];
        #pragma unroll
        for (int k2 = 0; k2 < 4; ++k2) {
            const int pos = (wave << 2) + k2;   // t = c*64 + pos
            const double thr = 0.7 * (sn[(c << 6) + pos] + 1e-8);
            int r = 0;
            // (a) partial current chunk: j in [c*64, t)
            u64 m = __ballot(lane < pos && v < thr);
            if (m) {                            // wave-uniform branch
                r = pos - (63 - __clzll(m));
            } else {
                // (b) nearest earlier chunk whose min qualifies
                u64 mc = __ballot(cm < thr);
                if (mc) {
                    int cc = 63 - __clzll(mc);  // wave-uniform
                    // (c) nearest element in that chunk (non-empty by cmin)
                    double v2 = sn[(cc << 6) + lane];
                    u64 m2 = __ballot(v2 < thr);
                    r = ((c - cc) << 6) + pos - (63 - __clzll(m2));
                }
            }
            res[k2] = (float)r;
        }
        if (lane == 0)
            ((float4*)out)[ci * 16 + wave] =
                make_float4(res[0], res[1], res[2], res[3]);
    }
}

extern "C" void kernel_launch(void* const* d_in, const int* in_sizes, int n_in,
                              void* d_out, int out_size, void* d_ws, size_t ws_size,
                              hipStream_t stream) {
    (void)d_ws; (void)ws_size; (void)n_in; (void)out_size;
    const float4* x4 = (const float4*)d_in[0];
    float* out = (float*)d_out;
    int nrows  = in_sizes[0] / 64;      // B*S = 16384
    int nchunk = nrows / 64;            // 256
    tc_onepass_kernel<<<nchunk, 1024, 0, stream>>>(x4, out);
}

// Round 5
// 56.323 us; speedup vs baseline: 1.7588x; 1.4591x over previous
//
#include <hip/hip_runtime.h>

// TcEmbedding: x (B=4, S=4096, D=64) f32.
// norms[b,t] = sum_d |x[b,t,d]|
// tc[b,t]   = t - j, j = nearest index < t with norms[j] < 0.7*(norms[t]+1e-8), else 0.
//
// FINAL (restore R7, best measured = 57.0-57.3us):
// Two dispatches; the kernel boundary is the only cheap device-wide barrier
// on this 8-XCD part. Ledger of alternatives, all measured worse:
//   R4  cooperative grid.sync      : +45us (graph-serialized exclusive launch)
//   R5  per-lane acquire spin      : +40us (acquire = cache maint. x8 XCDs)
//   R8  relaxed atomic counter bar : +14us (counter line ping-pong on fabric)
//   R6  sync-free full recompute   : kernel 43us
//   R11 recompute, scatter loads + per-lane row sums   : kernel ~40us
//   R12 recompute, coalesced loads + R7-A shuffle reduce: kernel ~39us
//     -> three independent recompute shapes all land 39-43us: the wall is
//        the worst block pulling its 1MB prefix through ONE CU's memory
//        path (~25 GB/s effective per-CU latency*MLP product), not the
//        load pattern or reduce shape. Recompute family closed.
//   R9  self-contained B           : +1.9us (32KB restage > rare L2 dip)
//   R10 16-block fusion            : kernel 57us (VGPR=20 serial chain)
// Breakdown at 57.2us: ~41us harness ws-poison fill (268MB, fixed - runs
// even when ws is unused, proven R10-R12) + ~2us restore/out-poison + ~14us
// A+gap+B (two ~3-4us dispatch-floor kernels + ~5us graph node gap).
// f64 norms/compares throughout: a compare flip near the 0.7 threshold
// changes tc by O(S) >> absmax tolerance (absmax 0 every round R1-R12).

#define SS 4096
typedef unsigned long long u64;

// ---------------- Kernel A: norms + chunk minima, one round per wave -------
template <typename T>
__global__ void __launch_bounds__(1024)
tc_norms_kernel(const float4* __restrict__ x4, T* __restrict__ nrm,
                T* __restrict__ cmn)
{
    __shared__ T smin[16];
    int ci   = blockIdx.x;              // chunk id = b*64 + c
    int wave = threadIdx.x >> 6;
    int lane = threadIdx.x & 63;
    int g    = lane >> 4;               // row within wave's 4 (0..3)
    int e    = lane & 15;               // float4 index within row

    int row = (ci << 6) + (wave << 2) + g;
    float4 p = x4[row * 16 + e];        // 64 lanes = 4 rows, 1KB coalesced
    T a = (T)fabsf(p.x) + (T)fabsf(p.y) + (T)fabsf(p.z) + (T)fabsf(p.w);
    #pragma unroll
    for (int off = 8; off > 0; off >>= 1)   // reduce within 16-lane group
        a += __shfl_xor(a, off, 64);
    if (e == 0) nrm[row] = a;               // lane e==0 holds the row norm

    // wave min over its 4 rows (valid only at e==0 lanes; mask others)
    T m = (e == 0) ? a : (T)1e300;
    {
        T o = __shfl_xor(m, 16, 64); m = (o < m) ? o : m;
        o   = __shfl_xor(m, 32, 64); m = (o < m) ? o : m;
    }
    if (lane == 0) smin[wave] = m;
    __syncthreads();
    if (threadIdx.x < 16) {                 // wave 0: min across 16 waves
        T m2 = smin[threadIdx.x];
        #pragma unroll
        for (int off = 8; off > 0; off >>= 1) {
            T o = __shfl_xor(m2, off, 64);
            m2 = (o < m2) ? o : m2;
        }
        if (threadIdx.x == 0) cmn[ci] = m2;
    }
}

// ---------------- Kernel B: two-level ballot search, LDS-staged ------------
template <typename T>
__global__ void __launch_bounds__(1024)
tc_scan_kernel(const T* __restrict__ nrm, const T* __restrict__ cmn,
               float* __restrict__ out)
{
    __shared__ T sn[64];                // own chunk's norms
    __shared__ T scm[64];               // row's 64 chunk minima
    int ci   = blockIdx.x;              // b*64 + c
    int b    = ci >> 6;
    int c    = ci & 63;
    int wave = threadIdx.x >> 6;
    int lane = threadIdx.x & 63;

    if (wave == 0)      sn[lane]  = nrm[(ci << 6) + lane];
    else if (wave == 1) scm[lane] = cmn[(b << 6) + lane];
    __syncthreads();

    T v  = sn[lane];
    T cm = scm[lane];
    float res[4];
    #pragma unroll
    for (int k = 0; k < 4; ++k) {
        int pos = (wave << 2) + k;      // t = c*64 + pos
        T thr = (T)0.7 * (sn[pos] + (T)1e-8);
        int r = 0;
        // (a) partial current chunk: j in [c*64, t)
        u64 m = __ballot(lane < pos && v < thr);
        if (m) {                        // wave-uniform (m is scalar)
            r = pos - (63 - __clzll(m));
        } else {
            // (b) nearest earlier chunk whose min qualifies
            u64 mc = __ballot(lane < c && cm < thr);
            if (mc) {
                int cc = 63 - __clzll(mc);                 // wave-uniform
                // (c) nearest element in that chunk (non-empty by cmin), L2
                T v2 = nrm[(b << 12) + (cc << 6) + lane];
                u64 m2 = __ballot(v2 < thr);
                r = ((c - cc) << 6) + pos - (63 - __clzll(m2));
            }
        }
        res[k] = (float)r;
    }
    if (lane == 0)
        ((float4*)out)[ci * 16 + wave] =
            make_float4(res[0], res[1], res[2], res[3]);
}

extern "C" void kernel_launch(void* const* d_in, const int* in_sizes, int n_in,
                              void* d_out, int out_size, void* d_ws, size_t ws_size,
                              hipStream_t stream) {
    const float4* x4 = (const float4*)d_in[0];
    float* out = (float*)d_out;
    int nrows  = in_sizes[0] / 64;      // B*S   = 16384
    int nchunk = nrows / 64;            // 256

    if (ws_size >= (size_t)(nrows + nchunk) * sizeof(double)) {
        double* nrm = (double*)d_ws;
        double* cmn = nrm + nrows;
        tc_norms_kernel<double><<<nchunk, 1024, 0, stream>>>(x4, nrm, cmn);
        tc_scan_kernel<double><<<nchunk, 1024, 0, stream>>>(nrm, cmn, out);
    } else {
        float* nrm = (float*)d_ws;
        float* cmn = nrm + nrows;
        tc_norms_kernel<float><<<nchunk, 1024, 0, stream>>>(x4, nrm, cmn);
        tc_scan_kernel<float><<<nchunk, 1024, 0, stream>>>(nrm, cmn, out);
    }
}